// Round 3
// baseline (1194.000 us; speedup 1.0000x reference)
//
#include <hip/hip_runtime.h>
#include <hip/hip_bf16.h>
#include <math.h>

typedef __attribute__((ext_vector_type(8))) short bf16x8;
typedef __attribute__((ext_vector_type(4))) float f32x4;
typedef __attribute__((ext_vector_type(8))) unsigned short u16x8;

#define M_ROWS 100000
#define MBLK   782    // ceil(100000/128)

static __device__ __forceinline__ unsigned short f2bf(float f) {
  union { float f; unsigned u; } cv; cv.f = f;
  unsigned u = cv.u;
  return (unsigned short)((u + 0x7fffu + ((u >> 16) & 1u)) >> 16);  // RNE
}
static __device__ __forceinline__ float bf2f(unsigned short u) {
  union { unsigned u; float f; } cv; cv.u = ((unsigned)u) << 16; return cv.f;
}

static __device__ __forceinline__ f32x4 mfma16(bf16x8 a, bf16x8 b, f32x4 c) {
  return __builtin_amdgcn_mfma_f32_16x16x32_bf16(a, b, c, 0, 0, 0);
}

// async global(per-lane) -> LDS(wave-uniform base + lane*16B) DMA
static __device__ __forceinline__ void gload_lds16(const unsigned short* g, unsigned short* l) {
  __builtin_amdgcn_global_load_lds((const __attribute__((address_space(1))) unsigned int*)g,
                                   (__attribute__((address_space(3))) unsigned int*)l, 16, 0, 0);
}

// ---------- prep: weights -> bf16 transposed; Ag init to b3; agg1 zero ----------
// Wct[c][k] = Wc[k][c]                                      (512x1024)
// Wat[g][k]: g=nb*128+cc: cc<64 -> W1[k][nb*64+cc], else W2[k][nb*64+cc-64]
__global__ void prep_kernel(const float* __restrict__ Wc, const float* __restrict__ W1,
                            const float* __restrict__ W2, const float* __restrict__ b3,
                            unsigned short* __restrict__ Wct, unsigned short* __restrict__ Wat,
                            float* __restrict__ Ag, float* __restrict__ agg1) {
  int i = blockIdx.x * blockDim.x + threadIdx.x;
  if (i < 524288) {
    int c = i >> 10, k = i & 1023;
    Wct[i] = f2bf(Wc[k * 512 + c]);
  } else if (i < 1048576) {
    int j = i - 524288;
    int g = j >> 10, k = j & 1023;
    int nb = g >> 7, cc = g & 127;
    float v = (cc < 64) ? W1[k * 256 + nb * 64 + cc] : W2[k * 256 + nb * 64 + cc - 64];
    Wat[j] = f2bf(v);
  } else if (i < 1248576) {
    int i2 = i - 1048576;          // 200000 entries of Ag
    Ag[i2] = b3[i2 & 1];
  } else if (i < 1249600) {
    agg1[i - 1248576] = 0.0f;
  }
}

// ---------- gemmA: 128x128 tile of [U1|U2] interleaved; epilogue -> partial A -> Ag ----------
__launch_bounds__(256)
__global__ void gemmA(const float* __restrict__ x, const unsigned short* __restrict__ Wat,
                      const float* __restrict__ b1, const float* __restrict__ b2,
                      const float* __restrict__ W3, float* __restrict__ Ag) {
  __shared__ unsigned short xl[128 * 32];   // 8KB [row][k]
  __shared__ unsigned short wl[128 * 32];   // 8KB [col][k]

  const int tid = threadIdx.x;
  const int lane = tid & 63, w = tid >> 6;
  const int lr = lane & 15, lg = lane >> 4;
  const int nb = blockIdx.x;                // 0..3
  const int m0 = blockIdx.y * 128;

  f32x4 acc[2][8];
#pragma unroll
  for (int m = 0; m < 2; m++)
#pragma unroll
    for (int n = 0; n < 8; n++) acc[m][n] = (f32x4){0.f, 0.f, 0.f, 0.f};

  // x staging: thread t -> row=t>>1, 16 k's at (t&1)*16
  const int xr = tid >> 1;
  const bool xvalid = (m0 + xr) < M_ROWS;
  const float* xsrc = x + (size_t)(m0 + xr) * 1024 + ((tid & 1) << 4);
  unsigned short* xdst = &xl[xr * 32 + ((tid & 1) << 4)];

  // W staging: 2 gload_lds issues per wave; issue i covers cols [w*32+i*16, +16)
  const unsigned short* wsrc0 = Wat + ((size_t)nb * 128 + w * 32 + (lane >> 2)) * 1024 + ((lane & 3) << 3);
  const unsigned short* wsrc1 = wsrc0 + (size_t)16 * 1024;
  unsigned short* wdst0 = &wl[w * 1024];
  unsigned short* wdst1 = &wl[w * 1024 + 512];

  const bf16x8* ap0 = (const bf16x8*)&xl[(w * 32 + lr) * 32 + lg * 8];
  const bf16x8* ap1 = (const bf16x8*)&xl[(w * 32 + 16 + lr) * 32 + lg * 8];
  const bf16x8* bp[8];
#pragma unroll
  for (int n = 0; n < 8; n++) bp[n] = (const bf16x8*)&wl[(n * 16 + lr) * 32 + lg * 8];

  for (int ks = 0; ks < 32; ks++) {
    const int k0 = ks * 32;
    gload_lds16(wsrc0 + k0, wdst0);
    gload_lds16(wsrc1 + k0, wdst1);
    float4 v0 = make_float4(0.f,0.f,0.f,0.f), v1 = v0, v2 = v0, v3 = v0;
    if (xvalid) {
      v0 = *(const float4*)(xsrc + k0);
      v1 = *(const float4*)(xsrc + k0 + 4);
      v2 = *(const float4*)(xsrc + k0 + 8);
      v3 = *(const float4*)(xsrc + k0 + 12);
    }
    u16x8 pa, pb;
    pa[0]=f2bf(v0.x); pa[1]=f2bf(v0.y); pa[2]=f2bf(v0.z); pa[3]=f2bf(v0.w);
    pa[4]=f2bf(v1.x); pa[5]=f2bf(v1.y); pa[6]=f2bf(v1.z); pa[7]=f2bf(v1.w);
    pb[0]=f2bf(v2.x); pb[1]=f2bf(v2.y); pb[2]=f2bf(v2.z); pb[3]=f2bf(v2.w);
    pb[4]=f2bf(v3.x); pb[5]=f2bf(v3.y); pb[6]=f2bf(v3.z); pb[7]=f2bf(v3.w);
    *(u16x8*)xdst = pa;
    *(u16x8*)(xdst + 8) = pb;
    __syncthreads();
    bf16x8 a0 = *ap0, a1 = *ap1;
#pragma unroll
    for (int n = 0; n < 8; n++) {
      bf16x8 bb = *bp[n];
      acc[0][n] = mfma16(a0, bb, acc[0][n]);
      acc[1][n] = mfma16(a1, bb, acc[1][n]);
    }
    __syncthreads();
  }

  // epilogue: u1 = acc[.][n], u2 = acc[.][n+4] (same thread, same j = nb*64+n*16+lr)
  float pA[2][4][2];
#pragma unroll
  for (int m = 0; m < 2; m++)
#pragma unroll
    for (int r = 0; r < 4; r++) { pA[m][r][0] = 0.f; pA[m][r][1] = 0.f; }

#pragma unroll
  for (int n = 0; n < 4; n++) {
    const int j = nb * 64 + n * 16 + lr;
    const float bb1 = b1[j], bb2 = b2[j];
    const float w30 = W3[j * 2], w31 = W3[j * 2 + 1];
#pragma unroll
    for (int m = 0; m < 2; m++)
#pragma unroll
      for (int r = 0; r < 4; r++) {
        float u1 = acc[m][n][r] + bb1;
        float u2 = acc[m][n + 4][r] + bb2;
        float av = tanhf(u1) * (1.0f / (1.0f + __expf(-u2)));
        pA[m][r][0] += av * w30;
        pA[m][r][1] += av * w31;
      }
  }
#pragma unroll
  for (int off = 1; off < 16; off <<= 1)
#pragma unroll
    for (int m = 0; m < 2; m++)
#pragma unroll
      for (int r = 0; r < 4; r++) {
        pA[m][r][0] += __shfl_xor(pA[m][r][0], off, 64);
        pA[m][r][1] += __shfl_xor(pA[m][r][1], off, 64);
      }
  if (lr == 0) {
#pragma unroll
    for (int m = 0; m < 2; m++)
#pragma unroll
      for (int r = 0; r < 4; r++) {
        int row = m0 + w * 32 + m * 16 + lg * 4 + r;
        if (row < M_ROWS) {
          atomicAdd(&Ag[(size_t)row * 2 + 0], pA[m][r][0]);
          atomicAdd(&Ag[(size_t)row * 2 + 1], pA[m][r][1]);
        }
      }
  }
}

// ---------- gemmH: 128x128 tile of H; epilogue h=relu -> agg partial (uses Ag) ----------
__launch_bounds__(256)
__global__ void gemmH(const float* __restrict__ x, const unsigned short* __restrict__ Wct,
                      const float* __restrict__ bc, const float* __restrict__ Ag,
                      float* __restrict__ aggP) {
  __shared__ unsigned short xl[128 * 32];
  __shared__ unsigned short wl[128 * 32];
  __shared__ float aggL[256];

  const int tid = threadIdx.x;
  const int lane = tid & 63, w = tid >> 6;
  const int lr = lane & 15, lg = lane >> 4;
  const int nb = blockIdx.x;                // 0..3 -> H cols [nb*128, +128)
  const int m0 = blockIdx.y * 128;

  f32x4 acc[2][8];
#pragma unroll
  for (int m = 0; m < 2; m++)
#pragma unroll
    for (int n = 0; n < 8; n++) acc[m][n] = (f32x4){0.f, 0.f, 0.f, 0.f};

  const int xr = tid >> 1;
  const bool xvalid = (m0 + xr) < M_ROWS;
  const float* xsrc = x + (size_t)(m0 + xr) * 1024 + ((tid & 1) << 4);
  unsigned short* xdst = &xl[xr * 32 + ((tid & 1) << 4)];

  const unsigned short* wsrc0 = Wct + ((size_t)nb * 128 + w * 32 + (lane >> 2)) * 1024 + ((lane & 3) << 3);
  const unsigned short* wsrc1 = wsrc0 + (size_t)16 * 1024;
  unsigned short* wdst0 = &wl[w * 1024];
  unsigned short* wdst1 = &wl[w * 1024 + 512];

  const bf16x8* ap0 = (const bf16x8*)&xl[(w * 32 + lr) * 32 + lg * 8];
  const bf16x8* ap1 = (const bf16x8*)&xl[(w * 32 + 16 + lr) * 32 + lg * 8];
  const bf16x8* bp[8];
#pragma unroll
  for (int n = 0; n < 8; n++) bp[n] = (const bf16x8*)&wl[(n * 16 + lr) * 32 + lg * 8];

  for (int ks = 0; ks < 32; ks++) {
    const int k0 = ks * 32;
    gload_lds16(wsrc0 + k0, wdst0);
    gload_lds16(wsrc1 + k0, wdst1);
    float4 v0 = make_float4(0.f,0.f,0.f,0.f), v1 = v0, v2 = v0, v3 = v0;
    if (xvalid) {
      v0 = *(const float4*)(xsrc + k0);
      v1 = *(const float4*)(xsrc + k0 + 4);
      v2 = *(const float4*)(xsrc + k0 + 8);
      v3 = *(const float4*)(xsrc + k0 + 12);
    }
    u16x8 pa, pb;
    pa[0]=f2bf(v0.x); pa[1]=f2bf(v0.y); pa[2]=f2bf(v0.z); pa[3]=f2bf(v0.w);
    pa[4]=f2bf(v1.x); pa[5]=f2bf(v1.y); pa[6]=f2bf(v1.z); pa[7]=f2bf(v1.w);
    pb[0]=f2bf(v2.x); pb[1]=f2bf(v2.y); pb[2]=f2bf(v2.z); pb[3]=f2bf(v2.w);
    pb[4]=f2bf(v3.x); pb[5]=f2bf(v3.y); pb[6]=f2bf(v3.z); pb[7]=f2bf(v3.w);
    *(u16x8*)xdst = pa;
    *(u16x8*)(xdst + 8) = pb;
    __syncthreads();
    bf16x8 a0 = *ap0, a1 = *ap1;
#pragma unroll
    for (int n = 0; n < 8; n++) {
      bf16x8 bb = *bp[n];
      acc[0][n] = mfma16(a0, bb, acc[0][n]);
      acc[1][n] = mfma16(a1, bb, acc[1][n]);
    }
    __syncthreads();
  }

  // epilogue: h=relu(u+bc); contrib[cout][col] += A[row][cout]*h
  float A0[2][4], A1[2][4];
#pragma unroll
  for (int m = 0; m < 2; m++)
#pragma unroll
    for (int r = 0; r < 4; r++) {
      int row = m0 + w * 32 + m * 16 + lg * 4 + r;
      bool valid = row < M_ROWS;
      A0[m][r] = valid ? Ag[(size_t)row * 2 + 0] : 0.f;
      A1[m][r] = valid ? Ag[(size_t)row * 2 + 1] : 0.f;
    }
  float c0[8], c1[8];
#pragma unroll
  for (int n = 0; n < 8; n++) { c0[n] = 0.f; c1[n] = 0.f; }
#pragma unroll
  for (int n = 0; n < 8; n++) {
    const float bcv = bc[nb * 128 + n * 16 + lr];
#pragma unroll
    for (int m = 0; m < 2; m++)
#pragma unroll
      for (int r = 0; r < 4; r++) {
        float h = fmaxf(acc[m][n][r] + bcv, 0.0f);
        c0[n] += A0[m][r] * h;
        c1[n] += A1[m][r] * h;
      }
  }
#pragma unroll
  for (int n = 0; n < 8; n++) {
    c0[n] += __shfl_xor(c0[n], 16, 64); c0[n] += __shfl_xor(c0[n], 32, 64);
    c1[n] += __shfl_xor(c1[n], 16, 64); c1[n] += __shfl_xor(c1[n], 32, 64);
  }
  aggL[tid] = 0.0f;
  __syncthreads();
  if (lane < 16) {
#pragma unroll
    for (int n = 0; n < 8; n++) {
      atomicAdd(&aggL[(n * 16 + lane) * 2 + 0], c0[n]);
      atomicAdd(&aggL[(n * 16 + lane) * 2 + 1], c1[n]);
    }
  }
  __syncthreads();
  aggP[(size_t)blockIdx.y * 1024 + nb * 256 + tid] = aggL[tid];
}

// ---------- top-k helpers: jax tie semantics (value desc/asc, index asc) ----------
template <bool MIN>
static __device__ __forceinline__ bool better(float v1, int i1, float v2, int i2) {
  if (MIN) return (v1 < v2) || (v1 == v2 && i1 < i2);
  else     return (v1 > v2) || (v1 == v2 && i1 < i2);
}

template <bool MIN>
static __device__ __forceinline__ void merge_lists(float* vL, int* iL, int t, int s) {
  float av[8], ov[8], mv[8];
  int ai[8], oi[8], mi[8];
#pragma unroll
  for (int p = 0; p < 8; p++) {
    av[p] = vL[t * 8 + p];       ai[p] = iL[t * 8 + p];
    ov[p] = vL[(t + s) * 8 + p]; oi[p] = iL[(t + s) * 8 + p];
  }
#pragma unroll
  for (int p = 0; p < 8; p++) {
    bool b = better<MIN>(av[p], ai[p], ov[7 - p], oi[7 - p]);
    mv[p] = b ? av[p] : ov[7 - p];
    mi[p] = b ? ai[p] : oi[7 - p];
  }
#define CE(i, j)                                                             \
  { if (!better<MIN>(mv[i], mi[i], mv[j], mi[j])) {                          \
      float tv = mv[i]; mv[i] = mv[j]; mv[j] = tv;                           \
      int tii = mi[i]; mi[i] = mi[j]; mi[j] = tii; } }
  CE(0, 4) CE(1, 5) CE(2, 6) CE(3, 7)
  CE(0, 2) CE(1, 3) CE(4, 6) CE(5, 7)
  CE(0, 1) CE(2, 3) CE(4, 5) CE(6, 7)
#undef CE
#pragma unroll
  for (int p = 0; p < 8; p++) { vL[t * 8 + p] = mv[p]; iL[t * 8 + p] = mi[p]; }
}

__launch_bounds__(256)
__global__ void topk_p1(const float* __restrict__ Ag, const int* __restrict__ bag_label,
                        float* __restrict__ tkv, int* __restrict__ tki,
                        float* __restrict__ bkv, int* __restrict__ bki) {
  __shared__ float tvL[256 * 8]; __shared__ int tiL[256 * 8];
  __shared__ float bvL[256 * 8]; __shared__ int biL[256 * 8];
  const int t = threadIdx.x;
  const int lab = bag_label[0];
  float tv[8], bv[8]; int ti[8], bi[8];
#pragma unroll
  for (int p = 0; p < 8; p++) {
    tv[p] = -3.4e38f; ti[p] = 0x7fffffff;
    bv[p] =  3.4e38f; bi[p] = 0x7fffffff;
  }
  for (int r = blockIdx.x * 256 + t; r < M_ROWS; r += 65536) {
    float v = Ag[(size_t)r * 2 + lab];
    {
      float cv = v; int ci = r;
#pragma unroll
      for (int p = 0; p < 8; p++) {
        bool b = (cv > tv[p]) || (cv == tv[p] && ci < ti[p]);
        if (b) { float t0 = tv[p]; int t1 = ti[p]; tv[p] = cv; ti[p] = ci; cv = t0; ci = t1; }
      }
    }
    {
      float cv = v; int ci = r;
#pragma unroll
      for (int p = 0; p < 8; p++) {
        bool b = (cv < bv[p]) || (cv == bv[p] && ci < bi[p]);
        if (b) { float t0 = bv[p]; int t1 = bi[p]; bv[p] = cv; bi[p] = ci; cv = t0; ci = t1; }
      }
    }
  }
#pragma unroll
  for (int p = 0; p < 8; p++) {
    tvL[t * 8 + p] = tv[p]; tiL[t * 8 + p] = ti[p];
    bvL[t * 8 + p] = bv[p]; biL[t * 8 + p] = bi[p];
  }
  __syncthreads();
  for (int s = 128; s > 0; s >>= 1) {
    if (t < s) {
      merge_lists<false>(tvL, tiL, t, s);
      merge_lists<true>(bvL, biL, t, s);
    }
    __syncthreads();
  }
  if (t < 8) {
    tkv[blockIdx.x * 8 + t] = tvL[t]; tki[blockIdx.x * 8 + t] = tiL[t];
    bkv[blockIdx.x * 8 + t] = bvL[t]; bki[blockIdx.x * 8 + t] = biL[t];
  }
}

__launch_bounds__(256)
__global__ void topk_p2(const float* __restrict__ tkv, const int* __restrict__ tki,
                        const float* __restrict__ bkv, const int* __restrict__ bki,
                        int* __restrict__ idxout, float* __restrict__ out) {
  __shared__ float tvL[256 * 8]; __shared__ int tiL[256 * 8];
  __shared__ float bvL[256 * 8]; __shared__ int biL[256 * 8];
  const int t = threadIdx.x;
#pragma unroll
  for (int p = 0; p < 8; p++) {
    tvL[t * 8 + p] = tkv[t * 8 + p]; tiL[t * 8 + p] = tki[t * 8 + p];
    bvL[t * 8 + p] = bkv[t * 8 + p]; biL[t * 8 + p] = bki[t * 8 + p];
  }
  __syncthreads();
  for (int s = 128; s > 0; s >>= 1) {
    if (t < s) {
      merge_lists<false>(tvL, tiL, t, s);
      merge_lists<true>(bvL, biL, t, s);
    }
    __syncthreads();
  }
  if (t == 0) {
#pragma unroll
    for (int p = 0; p < 8; p++) {
      idxout[p] = tiL[p];
      idxout[8 + p] = biL[p];
      out[37 + p] = 1.0f;
      out[45 + p] = 0.0f;
    }
  }
}

// ---------- hsel recompute: h rows for the 16 selected instances ----------
__launch_bounds__(256)
__global__ void hsel_kernel(const float* __restrict__ x, const unsigned short* __restrict__ Wct,
                            const float* __restrict__ bc, const int* __restrict__ idx,
                            float* __restrict__ hsel) {
  __shared__ float xrow[1024];
  const int t = threadIdx.x;
  const int r = idx[blockIdx.x];
  *(float4*)&xrow[t * 4] = *(const float4*)(x + (size_t)r * 1024 + t * 4);
  __syncthreads();
#pragma unroll
  for (int half = 0; half < 2; half++) {
    int c = t + half * 256;
    float s = 0.f;
    for (int k = 0; k < 1024; k += 8) {
      u16x8 w8 = *(const u16x8*)&Wct[(size_t)c * 1024 + k];
#pragma unroll
      for (int q = 0; q < 8; q++) s += bf2f(w8[q]) * xrow[k + q];
    }
    hsel[blockIdx.x * 512 + c] = fmaxf(s + bc[c], 0.0f);
  }
}

// ---------- reduce agg partials: agg1[g*2+cout] = sum over 782 mblks ----------
__launch_bounds__(256)
__global__ void reduce_kernel(const float* __restrict__ aggP, float* __restrict__ agg1) {
  int flat = (blockIdx.x & 3) * 256 + threadIdx.x;   // 0..1023
  int mg = blockIdx.x >> 2;                          // 0..7
  int b0 = mg * 98, b1 = min(MBLK, b0 + 98);
  float s = 0.f;
  for (int b = b0; b < b1; b++) s += aggP[(size_t)b * 1024 + flat];
  atomicAdd(&agg1[flat], s);
}

// ---------- slide score / softmax / argmax ----------
__launch_bounds__(512)
__global__ void score_kernel(const float* __restrict__ agg1, const float* __restrict__ Wbag,
                             const float* __restrict__ bbag, float* __restrict__ out) {
  __shared__ float r0[512], r1[512];
  int t = threadIdx.x;
  float wb = Wbag[t];
  r0[t] = agg1[t * 2 + 0] * wb;
  r1[t] = agg1[t * 2 + 1] * wb;
  __syncthreads();
  for (int off = 256; off > 0; off >>= 1) {
    if (t < off) { r0[t] += r0[t + off]; r1[t] += r1[t + off]; }
    __syncthreads();
  }
  if (t == 0) {
    float s0 = r0[0] + bbag[0];
    float s1 = r1[0] + bbag[0];
    out[0] = s0; out[1] = s1;
    out[2] = (s1 > s0) ? 1.0f : 0.0f;
    float mx = fmaxf(s0, s1);
    float e0 = __expf(s0 - mx), e1 = __expf(s1 - mx);
    out[3] = e0 / (e0 + e1);
    out[4] = e1 / (e0 + e1);
  }
}

// ---------- instance head: softmax(hsel @ Wins + bins) ----------
__launch_bounds__(512)
__global__ void ins_kernel(const float* __restrict__ hsel, const float* __restrict__ Wins,
                           const float* __restrict__ bins, float* __restrict__ out) {
  int lane = threadIdx.x & 63;
  int w = threadIdx.x >> 6;
#pragma unroll
  for (int si = 0; si < 2; si++) {
    int s = w * 2 + si;
    float z0 = 0.f, z1 = 0.f;
#pragma unroll
    for (int q = 0; q < 8; q++) {
      int c = lane * 8 + q;
      float h = hsel[s * 512 + c];
      z0 += h * Wins[c * 2 + 0];
      z1 += h * Wins[c * 2 + 1];
    }
#pragma unroll
    for (int off = 1; off < 64; off <<= 1) {
      z0 += __shfl_xor(z0, off, 64);
      z1 += __shfl_xor(z1, off, 64);
    }
    if (lane == 0) {
      z0 += bins[0]; z1 += bins[1];
      float mx = fmaxf(z0, z1);
      float e0 = __expf(z0 - mx), e1 = __expf(z1 - mx);
      float d = e0 + e1;
      out[5 + s * 2 + 0] = e0 / d;
      out[5 + s * 2 + 1] = e1 / d;
    }
  }
}

extern "C" void kernel_launch(void* const* d_in, const int* in_sizes, int n_in,
                              void* d_out, int out_size, void* d_ws, size_t ws_size,
                              hipStream_t stream) {
  (void)in_sizes; (void)n_in; (void)out_size; (void)ws_size;
  const float* x    = (const float*)d_in[0];
  const float* Wc   = (const float*)d_in[1];
  const float* bc   = (const float*)d_in[2];
  const float* W1   = (const float*)d_in[3];
  const float* b1   = (const float*)d_in[4];
  const float* W2   = (const float*)d_in[5];
  const float* b2   = (const float*)d_in[6];
  const float* W3   = (const float*)d_in[7];
  const float* b3   = (const float*)d_in[8];
  const float* Wbag = (const float*)d_in[9];
  const float* bbag = (const float*)d_in[10];
  const float* Wins = (const float*)d_in[11];
  const float* bins = (const float*)d_in[12];
  const int* bag_label = (const int*)d_in[13];
  float* out = (float*)d_out;
  char* ws = (char*)d_ws;

  // ws layout (bytes)
  unsigned short* Wct = (unsigned short*)(ws);              // 1,048,576
  unsigned short* Wat = (unsigned short*)(ws + 1048576);    // 1,048,576
  float* Ag   = (float*)(ws + 2097152);                     // 800,000
  float* aggP = (float*)(ws + 2897152);                     // 782*1024*4 = 3,203,072
  float* agg1 = (float*)(ws + 6100224);                     // 4,096
  int*   idx  = (int*)  (ws + 6104320);                     // 64
  float* hsel = (float*)(ws + 6104384);                     // 32,768
  float* tkv  = (float*)(ws + 6137152);                     // 8,192
  int*   tki  = (int*)  (ws + 6145344);                     // 8,192
  float* bkv  = (float*)(ws + 6153536);                     // 8,192
  int*   bki  = (int*)  (ws + 6161728);                     // 8,192

  prep_kernel<<<4882, 256, 0, stream>>>(Wc, W1, W2, b3, Wct, Wat, Ag, agg1);
  gemmA<<<dim3(4, MBLK), 256, 0, stream>>>(x, Wat, b1, b2, W3, Ag);
  topk_p1<<<256, 256, 0, stream>>>(Ag, bag_label, tkv, tki, bkv, bki);
  topk_p2<<<1, 256, 0, stream>>>(tkv, tki, bkv, bki, idx, out);
  gemmH<<<dim3(4, MBLK), 256, 0, stream>>>(x, Wct, bc, Ag, aggP);
  hsel_kernel<<<16, 256, 0, stream>>>(x, Wct, bc, idx, hsel);
  reduce_kernel<<<32, 256, 0, stream>>>(aggP, agg1);
  score_kernel<<<1, 512, 0, stream>>>(agg1, Wbag, bbag, out);
  ins_kernel<<<1, 512, 0, stream>>>(hsel, Wins, bins, out);
}